// Round 3
// baseline (139.617 us; speedup 1.0000x reference)
//
#include <hip/hip_runtime.h>
#include <cstdint>
#include <cstddef>

constexpr int BB = 64;
constexpr int NN = 1024;
constexpr int DD = 256;
constexpr int PP = 256;

typedef short short8 __attribute__((ext_vector_type(8)));
typedef float f32x4 __attribute__((ext_vector_type(4)));

__device__ __forceinline__ unsigned short f2bf(float f) {
    union { float f; uint32_t u; } v; v.f = f;
    uint32_t u = v.u;
    uint32_t r = (u + 0x7FFFu + ((u >> 16) & 1u)) >> 16;
    return (unsigned short)r;
}

// async global->LDS, 16B per lane, LDS dest = wave-uniform base + lane*16
__device__ __forceinline__ void async_load16(void* lds, const void* g) {
    __builtin_amdgcn_global_load_lds(
        (const __attribute__((address_space(1))) unsigned int*)g,
        (__attribute__((address_space(3))) unsigned int*)lds, 16, 0, 0);
}

// Stage a 64-row x 256-col bf16 tile (32KB) into LDS, XOR-swizzled via
// pre-swizzled SOURCE (LDS write stays linear). src_base = row 0 of tile.
__device__ __forceinline__ void stage_tile(const unsigned short* src_base,
                                           unsigned short* lds, int wv, int lane) {
    const char* base = (const char*)src_base;
    char* dst0 = (char*)lds + wv * 8192;
    #pragma unroll
    for (int i = 0; i < 8; i++) {
        int row = wv * 16 + i * 2 + (lane >> 5);
        int blk = (lane & 31) ^ (row & 7);
        async_load16(dst0 + i * 1024, base + row * 512 + blk * 16);
    }
}

// Read a 16B MFMA fragment from the swizzled tile. kidx = kc*4 + l4.
__device__ __forceinline__ short8 lds_frag(const unsigned short* lds, int row, int kidx) {
    uint32_t byte = (uint32_t)(row * 512) + (uint32_t)(((kidx ^ (row & 7)) & 31) << 4);
    return *reinterpret_cast<const short8*>(reinterpret_cast<const char*>(lds) + byte);
}

// ---- prep: wt[j][d] = bf16(w[d][j]) for j<256 -> w1, else w2 (transposed, bf16) ----
__global__ void prep_wt(const float* __restrict__ w1, const float* __restrict__ w2,
                        unsigned short* __restrict__ wt) {
    int j = blockIdx.x;        // 0..511
    int d = threadIdx.x;       // 0..255
    const float* w = (j < PP) ? w1 : w2;
    int jj = j & (PP - 1);
    wt[j * DD + d] = f2bf(w[d * PP + jj]);
}

// ---- q,k = sigmoid(x @ W)  +  xv = x @ w4, fused ----
// Grid (256, 2): blockIdx.y = half. Half 0 computes q (+xv), half 1 computes k.
// 4 waves; each wave owns 64 x-rows (4 sets of 16), x-fragments hoisted in regs.
__global__ __launch_bounds__(256) void qk_fused(const float* __restrict__ x,
                                                const unsigned short* __restrict__ wt,
                                                const float* __restrict__ w4,
                                                unsigned short* __restrict__ qb,
                                                unsigned short* __restrict__ kb,
                                                float* __restrict__ xv) {
    __shared__ __align__(16) unsigned short wtile[2][16384];   // 2 x 32KB
    const int t = threadIdx.x, wv = t >> 6, lane = t & 63, l15 = lane & 15, l4 = lane >> 4;
    const int rowBase = blockIdx.x * 256;
    const int half = blockIdx.y;

    stage_tile(wt + (size_t)(half * 4) * 64 * DD, wtile[0], wv, lane);   // first tile

    // hoist x fragments (bf16) + accumulate xv partials (f32)
    short8 xf[4][8];
    float xvp[4] = {0.f, 0.f, 0.f, 0.f};
    #pragma unroll
    for (int kc = 0; kc < 8; kc++) {
        float4 w4a = *reinterpret_cast<const float4*>(w4 + kc * 32 + l4 * 8);
        float4 w4b = *reinterpret_cast<const float4*>(w4 + kc * 32 + l4 * 8 + 4);
        #pragma unroll
        for (int s = 0; s < 4; s++) {
            const float* xr = x + (size_t)(rowBase + wv * 64 + s * 16 + l15) * DD + kc * 32 + l4 * 8;
            float4 a = *reinterpret_cast<const float4*>(xr);
            float4 b = *reinterpret_cast<const float4*>(xr + 4);
            xvp[s] += a.x * w4a.x + a.y * w4a.y + a.z * w4a.z + a.w * w4a.w
                    + b.x * w4b.x + b.y * w4b.y + b.z * w4b.z + b.w * w4b.w;
            short8 f;
            f[0] = (short)f2bf(a.x); f[1] = (short)f2bf(a.y);
            f[2] = (short)f2bf(a.z); f[3] = (short)f2bf(a.w);
            f[4] = (short)f2bf(b.x); f[5] = (short)f2bf(b.y);
            f[6] = (short)f2bf(b.z); f[7] = (short)f2bf(b.w);
            xf[s][kc] = f;
        }
    }
    // xv: reduce over the 4 lanes (l4 = 0..3) sharing each row; only half 0 writes
    if (half == 0) {
        #pragma unroll
        for (int s = 0; s < 4; s++) {
            xvp[s] += __shfl_xor(xvp[s], 16);
            xvp[s] += __shfl_xor(xvp[s], 32);
            if (l4 == 0) xv[rowBase + wv * 64 + s * 16 + l15] = xvp[s];
        }
    }

    __syncthreads();   // drains stage of first tile
    unsigned short* outp = half ? kb : qb;
    int buf = 0;
    for (int ct = 0; ct < 4; ct++) {
        if (ct + 1 < 4) stage_tile(wt + (size_t)(half * 4 + ct + 1) * 64 * DD, wtile[buf ^ 1], wv, lane);
        const int pc0 = ct * 64;
        #pragma unroll
        for (int st = 0; st < 4; st++) {
            f32x4 z = {0.f, 0.f, 0.f, 0.f};
            f32x4 acc[4] = {z, z, z, z};
            #pragma unroll
            for (int kc = 0; kc < 8; kc++) {
                short8 wf = lds_frag(wtile[buf], st * 16 + l15, kc * 4 + l4);
                #pragma unroll
                for (int s = 0; s < 4; s++)
                    acc[s] = __builtin_amdgcn_mfma_f32_16x16x32_bf16(wf, xf[s][kc], acc[s], 0, 0, 0);
            }
            // D: col(l15) = x-row, row(l4*4+r) = p-col -> 4 consecutive p per lane
            #pragma unroll
            for (int s = 0; s < 4; s++) {
                ushort4 pk;
                pk.x = f2bf(1.f / (1.f + __expf(-acc[s][0])));
                pk.y = f2bf(1.f / (1.f + __expf(-acc[s][1])));
                pk.z = f2bf(1.f / (1.f + __expf(-acc[s][2])));
                pk.w = f2bf(1.f / (1.f + __expf(-acc[s][3])));
                size_t off = (size_t)(rowBase + wv * 64 + s * 16 + l15) * PP + pc0 + st * 16 + l4 * 4;
                *reinterpret_cast<ushort4*>(outp + off) = pk;
            }
        }
        __syncthreads();
        buf ^= 1;
    }
}

// ---- partial logits: num/den over half the m-range (flash-style, scalar V) ----
// Grid (64, 4, 2): 256 q-rows per (b,qt), halves split the 16 m-tiles 8/8.
__global__ __launch_bounds__(256) void attn_logit(const unsigned short* __restrict__ qb,
                                                  const unsigned short* __restrict__ kb,
                                                  const float* __restrict__ xv,
                                                  float* __restrict__ numo,
                                                  float* __restrict__ deno) {
    __shared__ __align__(16) unsigned short kt[2][16384];   // 2 x 32KB
    __shared__ float xvs[512];
    const int b = blockIdx.x;
    const int qt = blockIdx.y;    // 4 tiles of 256 q-rows
    const int half = blockIdx.z;  // 8 m-tiles each
    const int t = threadIdx.x, wv = t >> 6, lane = t & 63, l15 = lane & 15, l4 = lane >> 4;
    const unsigned short* kbb = kb + ((size_t)b * NN + half * 512) * PP;

    stage_tile(kbb, kt[0], wv, lane);   // mt=0

    #pragma unroll
    for (int i = 0; i < 2; i++) xvs[t + i * 256] = xv[b * NN + half * 512 + t + i * 256];

    // hoist Q fragments: 4 sets x 8 kc
    short8 qf[4][8];
    #pragma unroll
    for (int s = 0; s < 4; s++) {
        const unsigned short* qrow = qb + ((size_t)(b * NN + qt * 256 + wv * 64 + s * 16 + l15)) * PP;
        #pragma unroll
        for (int kc = 0; kc < 8; kc++)
            qf[s][kc] = *reinterpret_cast<const short8*>(qrow + kc * 32 + l4 * 8);
    }

    float den[4][4], num[4][4];
    #pragma unroll
    for (int s = 0; s < 4; s++)
        #pragma unroll
        for (int r = 0; r < 4; r++) { den[s][r] = 0.f; num[s][r] = 0.f; }

    __syncthreads();   // drains stage of mt=0 + xvs
    int buf = 0;
    for (int mt = 0; mt < 8; mt++) {
        if (mt + 1 < 8) stage_tile(kbb + (size_t)(mt + 1) * 64 * PP, kt[buf ^ 1], wv, lane);
        #pragma unroll
        for (int st = 0; st < 4; st++) {
            f32x4 z = {0.f, 0.f, 0.f, 0.f};
            f32x4 a[4] = {z, z, z, z};
            #pragma unroll
            for (int kc = 0; kc < 8; kc++) {
                short8 kf = lds_frag(kt[buf], st * 16 + l15, kc * 4 + l4);
                #pragma unroll
                for (int s = 0; s < 4; s++)
                    a[s] = __builtin_amdgcn_mfma_f32_16x16x32_bf16(qf[s][kc], kf, a[s], 0, 0, 0);
            }
            float xvv = xvs[mt * 64 + st * 16 + l15];
            #pragma unroll
            for (int s = 0; s < 4; s++)
                #pragma unroll
                for (int r = 0; r < 4; r++) {
                    float e = __expf(a[s][r] * 0.0625f);   // s in (0,16): no max-subtract needed
                    den[s][r] += e;
                    num[s][r] += e * xvv;
                }
        }
        __syncthreads();
        buf ^= 1;
    }
    // reduce over the 16 lanes (l15 group) holding different m-columns
    #pragma unroll
    for (int s = 0; s < 4; s++)
        #pragma unroll
        for (int r = 0; r < 4; r++) {
            #pragma unroll
            for (int off = 1; off < 16; off <<= 1) {
                den[s][r] += __shfl_xor(den[s][r], off);
                num[s][r] += __shfl_xor(num[s][r], off);
            }
        }
    if (l15 == 0) {
        #pragma unroll
        for (int s = 0; s < 4; s++)
            #pragma unroll
            for (int r = 0; r < 4; r++) {
                int n = qt * 256 + wv * 64 + s * 16 + l4 * 4 + r;
                size_t o = (size_t)half * BB * NN + b * NN + n;
                numo[o] = num[s][r];
                deno[o] = den[s][r];
            }
    }
}

// ---- sentence partials: merge num/den halves -> softmax_n -> weighted row sum ----
// Grid (64, 16): 64 rows per chunk.
__global__ __launch_bounds__(256) void sent_partial(const float* __restrict__ x,
                                                    const float* __restrict__ numo,
                                                    const float* __restrict__ deno,
                                                    float* __restrict__ part) {
    __shared__ float al[64];
    __shared__ float redA[4];
    __shared__ float redB[4];
    const int b = blockIdx.x, ch = blockIdx.y;
    const int t = threadIdx.x;
    float l[4];
    #pragma unroll
    for (int i = 0; i < 4; i++) {
        int n = b * NN + t + i * 256;
        l[i] = (numo[n] + numo[BB * NN + n]) / (deno[n] + deno[BB * NN + n]);
    }
    float mx = fmaxf(fmaxf(l[0], l[1]), fmaxf(l[2], l[3]));
    #pragma unroll
    for (int off = 1; off < 64; off <<= 1) mx = fmaxf(mx, __shfl_xor(mx, off));
    if ((t & 63) == 0) redA[t >> 6] = mx;
    __syncthreads();
    mx = fmaxf(fmaxf(redA[0], redA[1]), fmaxf(redA[2], redA[3]));
    float e[4], es = 0.f;
    #pragma unroll
    for (int i = 0; i < 4; i++) { e[i] = __expf(l[i] - mx); es += e[i]; }
    #pragma unroll
    for (int off = 1; off < 64; off <<= 1) es += __shfl_xor(es, off);
    if ((t & 63) == 0) redB[t >> 6] = es;
    __syncthreads();
    float inv = 1.f / (redB[0] + redB[1] + redB[2] + redB[3]);
    // this chunk's 64 rows live at i = ch>>2, threads t in [(ch&3)*64, +64)
    int ei = ch >> 2;
    float sel = (ei == 0) ? e[0] : (ei == 1) ? e[1] : (ei == 2) ? e[2] : e[3];
    if ((t >> 6) == (ch & 3)) al[t & 63] = sel * inv;
    __syncthreads();
    float acc = 0.f;
    const float* xb = x + ((size_t)b * NN + ch * 64) * DD + t;
    #pragma unroll 8
    for (int n = 0; n < 64; n++)
        acc += al[n] * xb[(size_t)n * DD];   // coalesced: thread t reads col t
    part[(b * 16 + ch) * DD + t] = acc;
}

__global__ void sent_final(const float* __restrict__ part, float* __restrict__ out) {
    int b = blockIdx.x, t = threadIdx.x;
    float s = 0.f;
    #pragma unroll
    for (int c = 0; c < 16; c++) s += part[(b * 16 + c) * DD + t];
    out[b * DD + t] = s;
}

extern "C" void kernel_launch(void* const* d_in, const int* in_sizes, int n_in,
                              void* d_out, int out_size, void* d_ws, size_t ws_size,
                              hipStream_t stream) {
    (void)in_sizes; (void)n_in; (void)out_size; (void)ws_size;
    const float* x  = (const float*)d_in[0];
    const float* w1 = (const float*)d_in[1];
    const float* w2 = (const float*)d_in[2];
    const float* w4 = (const float*)d_in[3];
    float* out = (float*)d_out;

    char* ws = (char*)d_ws;
    const size_t MB = 1024 * 1024;
    unsigned short* qb   = (unsigned short*)(ws);                    // 32 MB
    unsigned short* kb   = (unsigned short*)(ws + 32 * MB);          // 32 MB
    unsigned short* wt   = (unsigned short*)(ws + 64 * MB);          // 256 KB
    float*          xv   = (float*)(ws + 64 * MB + 256 * 1024);     // 256 KB
    float*          num  = (float*)(ws + 64 * MB + 512 * 1024);     // 512 KB (2 halves)
    float*          den  = (float*)(ws + 64 * MB + 1024 * 1024);    // 512 KB (2 halves)
    float*          part = (float*)(ws);                             // aliases qb (done by then)

    prep_wt<<<dim3(2 * PP), dim3(DD), 0, stream>>>(w1, w2, wt);
    qk_fused<<<dim3(BB * NN / 256, 2), dim3(256), 0, stream>>>(x, wt, w4, qb, kb, xv);
    attn_logit<<<dim3(BB, 4, 2), dim3(256), 0, stream>>>(qb, kb, xv, num, den);
    sent_partial<<<dim3(BB, 16), dim3(256), 0, stream>>>(x, num, den, part);
    sent_final<<<dim3(BB), dim3(DD), 0, stream>>>(part, out);
}

// Round 4
// 138.266 us; speedup vs baseline: 1.0098x; 1.0098x over previous
//
#include <hip/hip_runtime.h>
#include <cstdint>
#include <cstddef>

constexpr int BB = 64;
constexpr int NN = 1024;
constexpr int DD = 256;
constexpr int PP = 256;

typedef short short8 __attribute__((ext_vector_type(8)));
typedef float f32x4 __attribute__((ext_vector_type(4)));

__device__ __forceinline__ unsigned short f2bf(float f) {
    union { float f; uint32_t u; } v; v.f = f;
    uint32_t u = v.u;
    uint32_t r = (u + 0x7FFFu + ((u >> 16) & 1u)) >> 16;
    return (unsigned short)r;
}

// async global->LDS, 16B per lane, LDS dest = wave-uniform base + lane*16
__device__ __forceinline__ void async_load16(void* lds, const void* g) {
    __builtin_amdgcn_global_load_lds(
        (const __attribute__((address_space(1))) unsigned int*)g,
        (__attribute__((address_space(3))) unsigned int*)lds, 16, 0, 0);
}

// Stage a 32-row x 256-col bf16 chunk (16KB) into LDS, XOR-swizzled via
// pre-swizzled SOURCE (LDS write stays linear).
__device__ __forceinline__ void stage32(const unsigned short* base,
                                        unsigned short* lds, int wv, int lane) {
    char* dst0 = (char*)lds + wv * 4096;
    #pragma unroll
    for (int i = 0; i < 4; i++) {
        int row = wv * 8 + i * 2 + (lane >> 5);
        int blk = (lane & 31) ^ (row & 7);
        async_load16(dst0 + i * 1024, (const char*)base + row * 512 + blk * 16);
    }
}

// Read a 16B MFMA fragment from the swizzled chunk. kidx = kc*4 + l4.
__device__ __forceinline__ short8 lds_frag(const unsigned short* lds, int row, int kidx) {
    uint32_t byte = (uint32_t)(row * 512) + (uint32_t)(((kidx ^ (row & 7)) & 31) << 4);
    return *reinterpret_cast<const short8*>(reinterpret_cast<const char*>(lds) + byte);
}

// ---- prep: wt[j][d] = bf16(w[d][j]) for j<256 -> w1, else w2 (transposed, bf16) ----
__global__ void prep_wt(const float* __restrict__ w1, const float* __restrict__ w2,
                        unsigned short* __restrict__ wt) {
    int j = blockIdx.x;        // 0..511
    int d = threadIdx.x;       // 0..255
    const float* w = (j < PP) ? w1 : w2;
    int jj = j & (PP - 1);
    wt[j * DD + d] = f2bf(w[d * PP + jj]);
}

// ---- q,k = sigmoid(x @ W)  +  xv = x @ w4, fused ----
// Grid 512 x 256thr (4 waves). Wave owns 32 x-rows (2 sets of 16), hoisted in
// regs. NO LDS: W fragments streamed from L2 per wave with 1-deep register
// prefetch. No barriers -> full latency hiding at 8 waves/CU.
__global__ __launch_bounds__(256) void qk_fused(const float* __restrict__ x,
                                                const unsigned short* __restrict__ wt,
                                                const float* __restrict__ w4,
                                                unsigned short* __restrict__ qb,
                                                unsigned short* __restrict__ kb,
                                                float* __restrict__ xv) {
    const int t = threadIdx.x, wv = t >> 6, lane = t & 63, l15 = lane & 15, l4 = lane >> 4;
    const int rowBase = blockIdx.x * 128 + wv * 32;

    // hoist x fragments (bf16) + accumulate xv partials (f32)
    short8 xf[2][8];
    float xvp[2] = {0.f, 0.f};
    #pragma unroll
    for (int kc = 0; kc < 8; kc++) {
        float4 w4a = *reinterpret_cast<const float4*>(w4 + kc * 32 + l4 * 8);
        float4 w4b = *reinterpret_cast<const float4*>(w4 + kc * 32 + l4 * 8 + 4);
        #pragma unroll
        for (int s = 0; s < 2; s++) {
            const float* xr = x + (size_t)(rowBase + s * 16 + l15) * DD + kc * 32 + l4 * 8;
            float4 a = *reinterpret_cast<const float4*>(xr);
            float4 b = *reinterpret_cast<const float4*>(xr + 4);
            xvp[s] += a.x * w4a.x + a.y * w4a.y + a.z * w4a.z + a.w * w4a.w
                    + b.x * w4b.x + b.y * w4b.y + b.z * w4b.z + b.w * w4b.w;
            short8 f;
            f[0] = (short)f2bf(a.x); f[1] = (short)f2bf(a.y);
            f[2] = (short)f2bf(a.z); f[3] = (short)f2bf(a.w);
            f[4] = (short)f2bf(b.x); f[5] = (short)f2bf(b.y);
            f[6] = (short)f2bf(b.z); f[7] = (short)f2bf(b.w);
            xf[s][kc] = f;
        }
    }
    // xv: reduce over l4 (lane bits 4,5)
    #pragma unroll
    for (int s = 0; s < 2; s++) {
        xvp[s] += __shfl_xor(xvp[s], 16);
        xvp[s] += __shfl_xor(xvp[s], 32);
        if (l4 == 0) xv[rowBase + s * 16 + l15] = xvp[s];
    }

    // W loop: 32 p-tiles of 16 cols, register prefetch 1 tile ahead
    short8 wf[8], wfn[8];
    #pragma unroll
    for (int kc = 0; kc < 8; kc++)
        wf[kc] = *reinterpret_cast<const short8*>(wt + (size_t)l15 * DD + kc * 32 + l4 * 8);
    #pragma unroll 2
    for (int p = 0; p < 32; p++) {
        if (p + 1 < 32) {
            #pragma unroll
            for (int kc = 0; kc < 8; kc++)
                wfn[kc] = *reinterpret_cast<const short8*>(
                    wt + (size_t)((p + 1) * 16 + l15) * DD + kc * 32 + l4 * 8);
        }
        f32x4 acc0 = {0.f, 0.f, 0.f, 0.f};
        f32x4 acc1 = {0.f, 0.f, 0.f, 0.f};
        #pragma unroll
        for (int kc = 0; kc < 8; kc++) {
            acc0 = __builtin_amdgcn_mfma_f32_16x16x32_bf16(wf[kc], xf[0][kc], acc0, 0, 0, 0);
            acc1 = __builtin_amdgcn_mfma_f32_16x16x32_bf16(wf[kc], xf[1][kc], acc1, 0, 0, 0);
        }
        // D: col(l15) = x-row, row(l4*4+r) = p-col -> 4 consecutive p per lane
        unsigned short* outp = (p < 16) ? qb : kb;
        const int pc = (p & 15) * 16 + l4 * 4;
        ushort4 pk;
        pk.x = f2bf(1.f / (1.f + __expf(-acc0[0])));
        pk.y = f2bf(1.f / (1.f + __expf(-acc0[1])));
        pk.z = f2bf(1.f / (1.f + __expf(-acc0[2])));
        pk.w = f2bf(1.f / (1.f + __expf(-acc0[3])));
        *reinterpret_cast<ushort4*>(outp + (size_t)(rowBase + l15) * PP + pc) = pk;
        pk.x = f2bf(1.f / (1.f + __expf(-acc1[0])));
        pk.y = f2bf(1.f / (1.f + __expf(-acc1[1])));
        pk.z = f2bf(1.f / (1.f + __expf(-acc1[2])));
        pk.w = f2bf(1.f / (1.f + __expf(-acc1[3])));
        *reinterpret_cast<ushort4*>(outp + (size_t)(rowBase + 16 + l15) * PP + pc) = pk;
        #pragma unroll
        for (int kc = 0; kc < 8; kc++) wf[kc] = wfn[kc];
    }
}

// ---- partial logits: num/den over half the m-range (flash-style, scalar V) ----
// Grid (16, 64): x = qt*2+half, y = b (16 consecutive blocks share b -> K in L2).
// Wave owns 32 q-rows; K streamed in 32-row LDS chunks (dbuf 2x16KB).
// 4 blocks/CU = 16 waves/CU.
__global__ __launch_bounds__(256, 4) void attn_logit(const unsigned short* __restrict__ qb,
                                                     const unsigned short* __restrict__ kb,
                                                     const float* __restrict__ xv,
                                                     float* __restrict__ numo,
                                                     float* __restrict__ deno) {
    __shared__ __align__(16) unsigned short kt[2][8192];   // 2 x 16KB
    __shared__ float xvs[512];
    const int qt = blockIdx.x >> 1, half = blockIdx.x & 1, b = blockIdx.y;
    const int t = threadIdx.x, wv = t >> 6, lane = t & 63, l15 = lane & 15, l4 = lane >> 4;
    const unsigned short* kbb = kb + ((size_t)b * NN + half * 512) * PP;

    stage32(kbb, kt[0], wv, lane);   // chunk 0

    xvs[t] = xv[b * NN + half * 512 + t];
    xvs[t + 256] = xv[b * NN + half * 512 + t + 256];

    // hoist Q fragments: 2 sets x 8 kc
    short8 qf[2][8];
    const int qrow0 = b * NN + qt * 128 + wv * 32;
    #pragma unroll
    for (int s = 0; s < 2; s++) {
        const unsigned short* qrow = qb + (size_t)(qrow0 + s * 16 + l15) * PP;
        #pragma unroll
        for (int kc = 0; kc < 8; kc++)
            qf[s][kc] = *reinterpret_cast<const short8*>(qrow + kc * 32 + l4 * 8);
    }

    float den[2][4], num[2][4];
    #pragma unroll
    for (int s = 0; s < 2; s++)
        #pragma unroll
        for (int r = 0; r < 4; r++) { den[s][r] = 0.f; num[s][r] = 0.f; }

    __syncthreads();   // drains stage of chunk 0 + xvs
    int buf = 0;
    for (int mc = 0; mc < 16; mc++) {
        if (mc + 1 < 16) stage32(kbb + (size_t)(mc + 1) * 32 * PP, kt[buf ^ 1], wv, lane);
        #pragma unroll
        for (int st = 0; st < 2; st++) {
            f32x4 a0 = {0.f, 0.f, 0.f, 0.f};
            f32x4 a1 = {0.f, 0.f, 0.f, 0.f};
            #pragma unroll
            for (int kc = 0; kc < 8; kc++) {
                short8 kf = lds_frag(kt[buf], st * 16 + l15, kc * 4 + l4);
                a0 = __builtin_amdgcn_mfma_f32_16x16x32_bf16(qf[0][kc], kf, a0, 0, 0, 0);
                a1 = __builtin_amdgcn_mfma_f32_16x16x32_bf16(qf[1][kc], kf, a1, 0, 0, 0);
            }
            float xvv = xvs[mc * 32 + st * 16 + l15];
            #pragma unroll
            for (int r = 0; r < 4; r++) {
                float e0 = __expf(a0[r] * 0.0625f);   // s in (0,16): no max-subtract needed
                den[0][r] += e0; num[0][r] += e0 * xvv;
                float e1 = __expf(a1[r] * 0.0625f);
                den[1][r] += e1; num[1][r] += e1 * xvv;
            }
        }
        __syncthreads();
        buf ^= 1;
    }
    // reduce over the 16 lanes (l15 group) holding different m-columns
    #pragma unroll
    for (int s = 0; s < 2; s++)
        #pragma unroll
        for (int r = 0; r < 4; r++) {
            #pragma unroll
            for (int off = 1; off < 16; off <<= 1) {
                den[s][r] += __shfl_xor(den[s][r], off);
                num[s][r] += __shfl_xor(num[s][r], off);
            }
        }
    if (l15 == 0) {
        #pragma unroll
        for (int s = 0; s < 2; s++)
            #pragma unroll
            for (int r = 0; r < 4; r++) {
                int n = qt * 128 + wv * 32 + s * 16 + l4 * 4 + r;
                size_t o = (size_t)half * BB * NN + (size_t)b * NN + n;
                numo[o] = num[s][r];
                deno[o] = den[s][r];
            }
    }
}

// ---- sentence partials: merge num/den halves -> softmax_n -> weighted row sum ----
// Grid (64, 16): 64 rows per chunk.
__global__ __launch_bounds__(256) void sent_partial(const float* __restrict__ x,
                                                    const float* __restrict__ numo,
                                                    const float* __restrict__ deno,
                                                    float* __restrict__ part) {
    __shared__ float al[64];
    __shared__ float redA[4];
    __shared__ float redB[4];
    const int b = blockIdx.x, ch = blockIdx.y;
    const int t = threadIdx.x;
    float l[4];
    #pragma unroll
    for (int i = 0; i < 4; i++) {
        int n = b * NN + t + i * 256;
        l[i] = (numo[n] + numo[BB * NN + n]) / (deno[n] + deno[BB * NN + n]);
    }
    float mx = fmaxf(fmaxf(l[0], l[1]), fmaxf(l[2], l[3]));
    #pragma unroll
    for (int off = 1; off < 64; off <<= 1) mx = fmaxf(mx, __shfl_xor(mx, off));
    if ((t & 63) == 0) redA[t >> 6] = mx;
    __syncthreads();
    mx = fmaxf(fmaxf(redA[0], redA[1]), fmaxf(redA[2], redA[3]));
    float e[4], es = 0.f;
    #pragma unroll
    for (int i = 0; i < 4; i++) { e[i] = __expf(l[i] - mx); es += e[i]; }
    #pragma unroll
    for (int off = 1; off < 64; off <<= 1) es += __shfl_xor(es, off);
    if ((t & 63) == 0) redB[t >> 6] = es;
    __syncthreads();
    float inv = 1.f / (redB[0] + redB[1] + redB[2] + redB[3]);
    // this chunk's 64 rows live at i = ch>>2, threads t in [(ch&3)*64, +64)
    int ei = ch >> 2;
    float sel = (ei == 0) ? e[0] : (ei == 1) ? e[1] : (ei == 2) ? e[2] : e[3];
    if ((t >> 6) == (ch & 3)) al[t & 63] = sel * inv;
    __syncthreads();
    float acc = 0.f;
    const float* xb = x + ((size_t)b * NN + ch * 64) * DD + t;
    #pragma unroll 8
    for (int n = 0; n < 64; n++)
        acc += al[n] * xb[(size_t)n * DD];   // coalesced: thread t reads col t
    part[(b * 16 + ch) * DD + t] = acc;
}

__global__ void sent_final(const float* __restrict__ part, float* __restrict__ out) {
    int b = blockIdx.x, t = threadIdx.x;
    float s = 0.f;
    #pragma unroll
    for (int c = 0; c < 16; c++) s += part[(b * 16 + c) * DD + t];
    out[b * DD + t] = s;
}

extern "C" void kernel_launch(void* const* d_in, const int* in_sizes, int n_in,
                              void* d_out, int out_size, void* d_ws, size_t ws_size,
                              hipStream_t stream) {
    (void)in_sizes; (void)n_in; (void)out_size; (void)ws_size;
    const float* x  = (const float*)d_in[0];
    const float* w1 = (const float*)d_in[1];
    const float* w2 = (const float*)d_in[2];
    const float* w4 = (const float*)d_in[3];
    float* out = (float*)d_out;

    char* ws = (char*)d_ws;
    const size_t MB = 1024 * 1024;
    unsigned short* qb   = (unsigned short*)(ws);                    // 32 MB
    unsigned short* kb   = (unsigned short*)(ws + 32 * MB);          // 32 MB
    unsigned short* wt   = (unsigned short*)(ws + 64 * MB);          // 256 KB
    float*          xv   = (float*)(ws + 64 * MB + 256 * 1024);     // 256 KB
    float*          num  = (float*)(ws + 64 * MB + 512 * 1024);     // 512 KB (2 halves)
    float*          den  = (float*)(ws + 64 * MB + 1024 * 1024);    // 512 KB (2 halves)
    float*          part = (float*)(ws);                             // aliases qb (dead by then)

    prep_wt<<<dim3(2 * PP), dim3(DD), 0, stream>>>(w1, w2, wt);
    qk_fused<<<dim3(BB * NN / 128), dim3(256), 0, stream>>>(x, wt, w4, qb, kb, xv);
    attn_logit<<<dim3(16, BB), dim3(256), 0, stream>>>(qb, kb, xv, num, den);
    sent_partial<<<dim3(BB, 16), dim3(256), 0, stream>>>(x, num, den, part);
    sent_final<<<dim3(BB), dim3(DD), 0, stream>>>(part, out);
}

// Round 5
// 107.142 us; speedup vs baseline: 1.3031x; 1.2905x over previous
//
#include <hip/hip_runtime.h>
#include <cstdint>
#include <cstddef>

constexpr int BB = 64;
constexpr int NN = 1024;
constexpr int DD = 256;
constexpr int PP = 256;

typedef short short8 __attribute__((ext_vector_type(8)));
typedef float f32x4 __attribute__((ext_vector_type(4)));

__device__ __forceinline__ unsigned short f2bf(float f) {
    union { float f; uint32_t u; } v; v.f = f;
    uint32_t u = v.u;
    uint32_t r = (u + 0x7FFFu + ((u >> 16) & 1u)) >> 16;
    return (unsigned short)r;
}

// async global->LDS, 16B per lane, LDS dest = wave-uniform base + lane*16
__device__ __forceinline__ void async_load16(void* lds, const void* g) {
    __builtin_amdgcn_global_load_lds(
        (const __attribute__((address_space(1))) unsigned int*)g,
        (__attribute__((address_space(3))) unsigned int*)lds, 16, 0, 0);
}

// Stage a 64-row x 256-col bf16 tile (32KB) into LDS, XOR-swizzled via
// pre-swizzled SOURCE (LDS write stays linear). 4 waves, 8 loads each.
__device__ __forceinline__ void stage_tile(const unsigned short* src_base,
                                           unsigned short* lds, int wv, int lane) {
    const char* base = (const char*)src_base;
    char* dst0 = (char*)lds + wv * 8192;
    #pragma unroll
    for (int i = 0; i < 8; i++) {
        int row = wv * 16 + i * 2 + (lane >> 5);
        int blk = (lane & 31) ^ (row & 7);
        async_load16(dst0 + i * 1024, base + row * 512 + blk * 16);
    }
}

// Stage a 32-row x 256-col bf16 chunk (16KB), 4 waves, 4 loads each.
__device__ __forceinline__ void stage32(const unsigned short* base,
                                        unsigned short* lds, int wv, int lane) {
    char* dst0 = (char*)lds + wv * 4096;
    #pragma unroll
    for (int i = 0; i < 4; i++) {
        int row = wv * 8 + i * 2 + (lane >> 5);
        int blk = (lane & 31) ^ (row & 7);
        async_load16(dst0 + i * 1024, (const char*)base + row * 512 + blk * 16);
    }
}

// Read a 16B MFMA fragment from the swizzled tile. kidx = kc*4 + l4.
__device__ __forceinline__ short8 lds_frag(const unsigned short* lds, int row, int kidx) {
    uint32_t byte = (uint32_t)(row * 512) + (uint32_t)(((kidx ^ (row & 7)) & 31) << 4);
    return *reinterpret_cast<const short8*>(reinterpret_cast<const char*>(lds) + byte);
}

// ---- prep: wt[j][d] = bf16(w[d][j]) for j<256 -> w1, else w2 (transposed, bf16) ----
__global__ void prep_wt(const float* __restrict__ w1, const float* __restrict__ w2,
                        unsigned short* __restrict__ wt) {
    int j = blockIdx.x;        // 0..511
    int d = threadIdx.x;       // 0..255
    const float* w = (j < PP) ? w1 : w2;
    int jj = j & (PP - 1);
    wt[j * DD + d] = f2bf(w[d * PP + jj]);
}

// ---- q,k = sigmoid(x @ W)  +  xv = x @ w4, fused ----
// Grid 512 x 256thr (4 waves). Wave owns 32 x-rows (2 sets of 16) hoisted in
// regs (64 VGPR). W staged per-BLOCK in LDS (8 tiles of 64 p-cols, dbuf) so the
// 4 waves share each 32KB stage. 2 blocks/CU hide the barriers.
__global__ __launch_bounds__(256) void qk_fused(const float* __restrict__ x,
                                                const unsigned short* __restrict__ wt,
                                                const float* __restrict__ w4,
                                                unsigned short* __restrict__ qb,
                                                unsigned short* __restrict__ kb,
                                                float* __restrict__ xv) {
    __shared__ __align__(16) unsigned short wtile[2][16384];   // 2 x 32KB
    const int t = threadIdx.x, wv = t >> 6, lane = t & 63, l15 = lane & 15, l4 = lane >> 4;
    const int rowBase = blockIdx.x * 128 + wv * 32;

    stage_tile(wt, wtile[0], wv, lane);   // ct=0

    // hoist x fragments (bf16) + accumulate xv partials (f32)
    short8 xf[2][8];
    float xvp[2] = {0.f, 0.f};
    #pragma unroll
    for (int kc = 0; kc < 8; kc++) {
        float4 w4a = *reinterpret_cast<const float4*>(w4 + kc * 32 + l4 * 8);
        float4 w4b = *reinterpret_cast<const float4*>(w4 + kc * 32 + l4 * 8 + 4);
        #pragma unroll
        for (int s = 0; s < 2; s++) {
            const float* xr = x + (size_t)(rowBase + s * 16 + l15) * DD + kc * 32 + l4 * 8;
            float4 a = *reinterpret_cast<const float4*>(xr);
            float4 b = *reinterpret_cast<const float4*>(xr + 4);
            xvp[s] += a.x * w4a.x + a.y * w4a.y + a.z * w4a.z + a.w * w4a.w
                    + b.x * w4b.x + b.y * w4b.y + b.z * w4b.z + b.w * w4b.w;
            short8 f;
            f[0] = (short)f2bf(a.x); f[1] = (short)f2bf(a.y);
            f[2] = (short)f2bf(a.z); f[3] = (short)f2bf(a.w);
            f[4] = (short)f2bf(b.x); f[5] = (short)f2bf(b.y);
            f[6] = (short)f2bf(b.z); f[7] = (short)f2bf(b.w);
            xf[s][kc] = f;
        }
    }
    // xv: reduce over l4 (lane bits 4,5); rows are uniquely owned -> write
    #pragma unroll
    for (int s = 0; s < 2; s++) {
        xvp[s] += __shfl_xor(xvp[s], 16);
        xvp[s] += __shfl_xor(xvp[s], 32);
        if (l4 == 0) xv[rowBase + s * 16 + l15] = xvp[s];
    }

    __syncthreads();   // drains stage of ct=0
    int buf = 0;
    for (int ct = 0; ct < 8; ct++) {
        if (ct + 1 < 8) stage_tile(wt + (size_t)(ct + 1) * 64 * DD, wtile[buf ^ 1], wv, lane);
        unsigned short* outp = (ct < 4) ? qb : kb;
        const int pc0 = (ct & 3) * 64;
        #pragma unroll
        for (int st = 0; st < 4; st++) {
            f32x4 acc0 = {0.f, 0.f, 0.f, 0.f};
            f32x4 acc1 = {0.f, 0.f, 0.f, 0.f};
            #pragma unroll
            for (int kc = 0; kc < 8; kc++) {
                short8 wf = lds_frag(wtile[buf], st * 16 + l15, kc * 4 + l4);
                acc0 = __builtin_amdgcn_mfma_f32_16x16x32_bf16(wf, xf[0][kc], acc0, 0, 0, 0);
                acc1 = __builtin_amdgcn_mfma_f32_16x16x32_bf16(wf, xf[1][kc], acc1, 0, 0, 0);
            }
            // D: col(l15) = x-row, row(l4*4+r) = p-col -> 4 consecutive p per lane
            const int pc = pc0 + st * 16 + l4 * 4;
            ushort4 pk;
            pk.x = f2bf(1.f / (1.f + __expf(-acc0[0])));
            pk.y = f2bf(1.f / (1.f + __expf(-acc0[1])));
            pk.z = f2bf(1.f / (1.f + __expf(-acc0[2])));
            pk.w = f2bf(1.f / (1.f + __expf(-acc0[3])));
            *reinterpret_cast<ushort4*>(outp + (size_t)(rowBase + l15) * PP + pc) = pk;
            pk.x = f2bf(1.f / (1.f + __expf(-acc1[0])));
            pk.y = f2bf(1.f / (1.f + __expf(-acc1[1])));
            pk.z = f2bf(1.f / (1.f + __expf(-acc1[2])));
            pk.w = f2bf(1.f / (1.f + __expf(-acc1[3])));
            *reinterpret_cast<ushort4*>(outp + (size_t)(rowBase + 16 + l15) * PP + pc) = pk;
        }
        __syncthreads();
        buf ^= 1;
    }
}

// ---- partial logits: num/den over half the m-range (flash-style, scalar V) ----
// Grid (16, 64): x = qt*2+half, y = b (16 consecutive blocks share b -> K in L2).
// Wave owns 32 q-rows; K streamed in 32-row LDS chunks (dbuf 2x16KB).
// 4 blocks/CU = 16 waves/CU.
__global__ __launch_bounds__(256, 4) void attn_logit(const unsigned short* __restrict__ qb,
                                                     const unsigned short* __restrict__ kb,
                                                     const float* __restrict__ xv,
                                                     float* __restrict__ numo,
                                                     float* __restrict__ deno) {
    __shared__ __align__(16) unsigned short kt[2][8192];   // 2 x 16KB
    __shared__ float xvs[512];
    const int qt = blockIdx.x >> 1, half = blockIdx.x & 1, b = blockIdx.y;
    const int t = threadIdx.x, wv = t >> 6, lane = t & 63, l15 = lane & 15, l4 = lane >> 4;
    const unsigned short* kbb = kb + ((size_t)b * NN + half * 512) * PP;

    stage32(kbb, kt[0], wv, lane);   // chunk 0

    xvs[t] = xv[b * NN + half * 512 + t];
    xvs[t + 256] = xv[b * NN + half * 512 + t + 256];

    // hoist Q fragments: 2 sets x 8 kc
    short8 qf[2][8];
    const int qrow0 = b * NN + qt * 128 + wv * 32;
    #pragma unroll
    for (int s = 0; s < 2; s++) {
        const unsigned short* qrow = qb + (size_t)(qrow0 + s * 16 + l15) * PP;
        #pragma unroll
        for (int kc = 0; kc < 8; kc++)
            qf[s][kc] = *reinterpret_cast<const short8*>(qrow + kc * 32 + l4 * 8);
    }

    float den[2][4], num[2][4];
    #pragma unroll
    for (int s = 0; s < 2; s++)
        #pragma unroll
        for (int r = 0; r < 4; r++) { den[s][r] = 0.f; num[s][r] = 0.f; }

    __syncthreads();   // drains stage of chunk 0 + xvs
    int buf = 0;
    for (int mc = 0; mc < 16; mc++) {
        if (mc + 1 < 16) stage32(kbb + (size_t)(mc + 1) * 32 * PP, kt[buf ^ 1], wv, lane);
        #pragma unroll
        for (int st = 0; st < 2; st++) {
            f32x4 a0 = {0.f, 0.f, 0.f, 0.f};
            f32x4 a1 = {0.f, 0.f, 0.f, 0.f};
            #pragma unroll
            for (int kc = 0; kc < 8; kc++) {
                short8 kf = lds_frag(kt[buf], st * 16 + l15, kc * 4 + l4);
                a0 = __builtin_amdgcn_mfma_f32_16x16x32_bf16(qf[0][kc], kf, a0, 0, 0, 0);
                a1 = __builtin_amdgcn_mfma_f32_16x16x32_bf16(qf[1][kc], kf, a1, 0, 0, 0);
            }
            float xvv = xvs[mc * 32 + st * 16 + l15];
            #pragma unroll
            for (int r = 0; r < 4; r++) {
                float e0 = __expf(a0[r] * 0.0625f);   // s in (0,16): no max-subtract needed
                den[0][r] += e0; num[0][r] += e0 * xvv;
                float e1 = __expf(a1[r] * 0.0625f);
                den[1][r] += e1; num[1][r] += e1 * xvv;
            }
        }
        __syncthreads();
        buf ^= 1;
    }
    // reduce over the 16 lanes (l15 group) holding different m-columns
    #pragma unroll
    for (int s = 0; s < 2; s++)
        #pragma unroll
        for (int r = 0; r < 4; r++) {
            #pragma unroll
            for (int off = 1; off < 16; off <<= 1) {
                den[s][r] += __shfl_xor(den[s][r], off);
                num[s][r] += __shfl_xor(num[s][r], off);
            }
        }
    if (l15 == 0) {
        #pragma unroll
        for (int s = 0; s < 2; s++)
            #pragma unroll
            for (int r = 0; r < 4; r++) {
                int n = qt * 128 + wv * 32 + s * 16 + l4 * 4 + r;
                size_t o = (size_t)half * BB * NN + (size_t)b * NN + n;
                numo[o] = num[s][r];
                deno[o] = den[s][r];
            }
    }
}

// ---- sentence partials: merge num/den halves -> softmax_n -> weighted row sum ----
// Grid (64, 16): 64 rows per chunk.
__global__ __launch_bounds__(256) void sent_partial(const float* __restrict__ x,
                                                    const float* __restrict__ numo,
                                                    const float* __restrict__ deno,
                                                    float* __restrict__ part) {
    __shared__ float al[64];
    __shared__ float redA[4];
    __shared__ float redB[4];
    const int b = blockIdx.x, ch = blockIdx.y;
    const int t = threadIdx.x;
    float l[4];
    #pragma unroll
    for (int i = 0; i < 4; i++) {
        int n = b * NN + t + i * 256;
        l[i] = (numo[n] + numo[BB * NN + n]) / (deno[n] + deno[BB * NN + n]);
    }
    float mx = fmaxf(fmaxf(l[0], l[1]), fmaxf(l[2], l[3]));
    #pragma unroll
    for (int off = 1; off < 64; off <<= 1) mx = fmaxf(mx, __shfl_xor(mx, off));
    if ((t & 63) == 0) redA[t >> 6] = mx;
    __syncthreads();
    mx = fmaxf(fmaxf(redA[0], redA[1]), fmaxf(redA[2], redA[3]));
    float e[4], es = 0.f;
    #pragma unroll
    for (int i = 0; i < 4; i++) { e[i] = __expf(l[i] - mx); es += e[i]; }
    #pragma unroll
    for (int off = 1; off < 64; off <<= 1) es += __shfl_xor(es, off);
    if ((t & 63) == 0) redB[t >> 6] = es;
    __syncthreads();
    float inv = 1.f / (redB[0] + redB[1] + redB[2] + redB[3]);
    // this chunk's 64 rows live at i = ch>>2, threads t in [(ch&3)*64, +64)
    int ei = ch >> 2;
    float sel = (ei == 0) ? e[0] : (ei == 1) ? e[1] : (ei == 2) ? e[2] : e[3];
    if ((t >> 6) == (ch & 3)) al[t & 63] = sel * inv;
    __syncthreads();
    float acc = 0.f;
    const float* xb = x + ((size_t)b * NN + ch * 64) * DD + t;
    #pragma unroll 8
    for (int n = 0; n < 64; n++)
        acc += al[n] * xb[(size_t)n * DD];   // coalesced: thread t reads col t
    part[(b * 16 + ch) * DD + t] = acc;
}

__global__ void sent_final(const float* __restrict__ part, float* __restrict__ out) {
    int b = blockIdx.x, t = threadIdx.x;
    float s = 0.f;
    #pragma unroll
    for (int c = 0; c < 16; c++) s += part[(b * 16 + c) * DD + t];
    out[b * DD + t] = s;
}

extern "C" void kernel_launch(void* const* d_in, const int* in_sizes, int n_in,
                              void* d_out, int out_size, void* d_ws, size_t ws_size,
                              hipStream_t stream) {
    (void)in_sizes; (void)n_in; (void)out_size; (void)ws_size;
    const float* x  = (const float*)d_in[0];
    const float* w1 = (const float*)d_in[1];
    const float* w2 = (const float*)d_in[2];
    const float* w4 = (const float*)d_in[3];
    float* out = (float*)d_out;

    char* ws = (char*)d_ws;
    const size_t MB = 1024 * 1024;
    unsigned short* qb   = (unsigned short*)(ws);                    // 32 MB
    unsigned short* kb   = (unsigned short*)(ws + 32 * MB);          // 32 MB
    unsigned short* wt   = (unsigned short*)(ws + 64 * MB);          // 256 KB
    float*          xv   = (float*)(ws + 64 * MB + 256 * 1024);     // 256 KB
    float*          num  = (float*)(ws + 64 * MB + 512 * 1024);     // 512 KB (2 halves)
    float*          den  = (float*)(ws + 64 * MB + 1024 * 1024);    // 512 KB (2 halves)
    float*          part = (float*)(ws);                             // aliases qb (dead by then)

    prep_wt<<<dim3(2 * PP), dim3(DD), 0, stream>>>(w1, w2, wt);
    qk_fused<<<dim3(BB * NN / 128), dim3(256), 0, stream>>>(x, wt, w4, qb, kb, xv);
    attn_logit<<<dim3(16, BB), dim3(256), 0, stream>>>(qb, kb, xv, num, den);
    sent_partial<<<dim3(BB, 16), dim3(256), 0, stream>>>(x, num, den, part);
    sent_final<<<dim3(BB), dim3(DD), 0, stream>>>(part, out);
}

// Round 6
// 104.012 us; speedup vs baseline: 1.3423x; 1.0301x over previous
//
#include <hip/hip_runtime.h>
#include <hip/hip_bf16.h>
#include <cstdint>
#include <cstddef>

constexpr int BB = 64;
constexpr int NN = 1024;
constexpr int DD = 256;
constexpr int PP = 256;

typedef short short8 __attribute__((ext_vector_type(8)));
typedef float f32x4 __attribute__((ext_vector_type(4)));

// RNE f32->bf16 via the HIP cast so the compiler can fuse pairs into
// v_cvt_pk_bf16_f32 (manual bit-twiddling defeats the pattern-match).
__device__ __forceinline__ unsigned short f2bf(float f) {
    union { __hip_bfloat16 h; unsigned short u; } v;
    v.h = __float2bfloat16(f);
    return v.u;
}

// async global->LDS, 16B per lane, LDS dest = wave-uniform base + lane*16
__device__ __forceinline__ void async_load16(void* lds, const void* g) {
    __builtin_amdgcn_global_load_lds(
        (const __attribute__((address_space(1))) unsigned int*)g,
        (__attribute__((address_space(3))) unsigned int*)lds, 16, 0, 0);
}

// Stage a 64-row x 256-col bf16 tile (32KB) into LDS, XOR-swizzled via
// pre-swizzled SOURCE (LDS write stays linear). 4 waves, 8 loads each.
__device__ __forceinline__ void stage_tile(const unsigned short* src_base,
                                           unsigned short* lds, int wv, int lane) {
    const char* base = (const char*)src_base;
    char* dst0 = (char*)lds + wv * 8192;
    #pragma unroll
    for (int i = 0; i < 8; i++) {
        int row = wv * 16 + i * 2 + (lane >> 5);
        int blk = (lane & 31) ^ (row & 7);
        async_load16(dst0 + i * 1024, base + row * 512 + blk * 16);
    }
}

// Stage a 32-row x 256-col bf16 chunk (16KB), 4 waves, 4 loads each.
__device__ __forceinline__ void stage32(const unsigned short* base,
                                        unsigned short* lds, int wv, int lane) {
    char* dst0 = (char*)lds + wv * 4096;
    #pragma unroll
    for (int i = 0; i < 4; i++) {
        int row = wv * 8 + i * 2 + (lane >> 5);
        int blk = (lane & 31) ^ (row & 7);
        async_load16(dst0 + i * 1024, (const char*)base + row * 512 + blk * 16);
    }
}

// Read a 16B MFMA fragment from the swizzled tile. kidx = kc*4 + l4.
__device__ __forceinline__ short8 lds_frag(const unsigned short* lds, int row, int kidx) {
    uint32_t byte = (uint32_t)(row * 512) + (uint32_t)(((kidx ^ (row & 7)) & 31) << 4);
    return *reinterpret_cast<const short8*>(reinterpret_cast<const char*>(lds) + byte);
}

// ---- prep: wt[j][d] = bf16(w[d][j]) for j<256 -> w1, else w2 (transposed, bf16) ----
__global__ void prep_wt(const float* __restrict__ w1, const float* __restrict__ w2,
                        unsigned short* __restrict__ wt) {
    int j = blockIdx.x;        // 0..511
    int d = threadIdx.x;       // 0..255
    const float* w = (j < PP) ? w1 : w2;
    int jj = j & (PP - 1);
    wt[j * DD + d] = f2bf(w[d * PP + jj]);
}

// ---- q,k = sigmoid(x @ W)  +  xv = x @ w4, fused ----
// Grid 512 x 256thr (4 waves). Wave owns 32 x-rows (2 sets of 16) hoisted in
// regs (64 VGPR). W staged per-BLOCK in LDS (8 tiles of 64 p-cols, dbuf) so the
// 4 waves share each 32KB stage. 2 blocks/CU hide the barriers.
__global__ __launch_bounds__(256) void qk_fused(const float* __restrict__ x,
                                                const unsigned short* __restrict__ wt,
                                                const float* __restrict__ w4,
                                                unsigned short* __restrict__ qb,
                                                unsigned short* __restrict__ kb,
                                                float* __restrict__ xv) {
    __shared__ __align__(16) unsigned short wtile[2][16384];   // 2 x 32KB
    const int t = threadIdx.x, wv = t >> 6, lane = t & 63, l15 = lane & 15, l4 = lane >> 4;
    const int rowBase = blockIdx.x * 128 + wv * 32;

    stage_tile(wt, wtile[0], wv, lane);   // ct=0

    // hoist x fragments (bf16) + accumulate xv partials (f32)
    short8 xf[2][8];
    float xvp[2] = {0.f, 0.f};
    #pragma unroll
    for (int kc = 0; kc < 8; kc++) {
        float4 w4a = *reinterpret_cast<const float4*>(w4 + kc * 32 + l4 * 8);
        float4 w4b = *reinterpret_cast<const float4*>(w4 + kc * 32 + l4 * 8 + 4);
        #pragma unroll
        for (int s = 0; s < 2; s++) {
            const float* xr = x + (size_t)(rowBase + s * 16 + l15) * DD + kc * 32 + l4 * 8;
            float4 a = *reinterpret_cast<const float4*>(xr);
            float4 b = *reinterpret_cast<const float4*>(xr + 4);
            xvp[s] += a.x * w4a.x + a.y * w4a.y + a.z * w4a.z + a.w * w4a.w
                    + b.x * w4b.x + b.y * w4b.y + b.z * w4b.z + b.w * w4b.w;
            short8 f;
            f[0] = (short)f2bf(a.x); f[1] = (short)f2bf(a.y);
            f[2] = (short)f2bf(a.z); f[3] = (short)f2bf(a.w);
            f[4] = (short)f2bf(b.x); f[5] = (short)f2bf(b.y);
            f[6] = (short)f2bf(b.z); f[7] = (short)f2bf(b.w);
            xf[s][kc] = f;
        }
    }
    // xv: reduce over l4 (lane bits 4,5); rows are uniquely owned -> write
    #pragma unroll
    for (int s = 0; s < 2; s++) {
        xvp[s] += __shfl_xor(xvp[s], 16);
        xvp[s] += __shfl_xor(xvp[s], 32);
        if (l4 == 0) xv[rowBase + s * 16 + l15] = xvp[s];
    }

    __syncthreads();   // drains stage of ct=0
    int buf = 0;
    for (int ct = 0; ct < 8; ct++) {
        if (ct + 1 < 8) stage_tile(wt + (size_t)(ct + 1) * 64 * DD, wtile[buf ^ 1], wv, lane);
        unsigned short* outp = (ct < 4) ? qb : kb;
        const int pc0 = (ct & 3) * 64;
        #pragma unroll
        for (int st = 0; st < 4; st++) {
            f32x4 acc0 = {0.f, 0.f, 0.f, 0.f};
            f32x4 acc1 = {0.f, 0.f, 0.f, 0.f};
            #pragma unroll
            for (int kc = 0; kc < 8; kc++) {
                short8 wf = lds_frag(wtile[buf], st * 16 + l15, kc * 4 + l4);
                acc0 = __builtin_amdgcn_mfma_f32_16x16x32_bf16(wf, xf[0][kc], acc0, 0, 0, 0);
                acc1 = __builtin_amdgcn_mfma_f32_16x16x32_bf16(wf, xf[1][kc], acc1, 0, 0, 0);
            }
            // D: col(l15) = x-row, row(l4*4+r) = p-col -> 4 consecutive p per lane
            const int pc = pc0 + st * 16 + l4 * 4;
            ushort4 pk;
            pk.x = f2bf(1.f / (1.f + __expf(-acc0[0])));
            pk.y = f2bf(1.f / (1.f + __expf(-acc0[1])));
            pk.z = f2bf(1.f / (1.f + __expf(-acc0[2])));
            pk.w = f2bf(1.f / (1.f + __expf(-acc0[3])));
            *reinterpret_cast<ushort4*>(outp + (size_t)(rowBase + l15) * PP + pc) = pk;
            pk.x = f2bf(1.f / (1.f + __expf(-acc1[0])));
            pk.y = f2bf(1.f / (1.f + __expf(-acc1[1])));
            pk.z = f2bf(1.f / (1.f + __expf(-acc1[2])));
            pk.w = f2bf(1.f / (1.f + __expf(-acc1[3])));
            *reinterpret_cast<ushort4*>(outp + (size_t)(rowBase + 16 + l15) * PP + pc) = pk;
        }
        __syncthreads();
        buf ^= 1;
    }
}

// ---- partial logits: num/den over half the m-range (flash-style, scalar V) ----
// Grid (8, 64): x = qt*2+half, y = b. Wave owns 64 q-rows (qf[4][8] = 128 VGPR)
// so each K-fragment ds_read feeds 4 MFMAs. K streamed in 32-row LDS chunks
// (dbuf 2x16KB). 2048 waves = 8/CU (2 waves/SIMD at ~200 VGPR).
__global__ __launch_bounds__(256, 2) void attn_logit(const unsigned short* __restrict__ qb,
                                                     const unsigned short* __restrict__ kb,
                                                     const float* __restrict__ xv,
                                                     float* __restrict__ numo,
                                                     float* __restrict__ deno) {
    __shared__ __align__(16) unsigned short kt[2][8192];   // 2 x 16KB
    __shared__ float xvs[512];
    const int qt = blockIdx.x >> 1, half = blockIdx.x & 1, b = blockIdx.y;
    const int t = threadIdx.x, wv = t >> 6, lane = t & 63, l15 = lane & 15, l4 = lane >> 4;
    const unsigned short* kbb = kb + ((size_t)b * NN + half * 512) * PP;

    stage32(kbb, kt[0], wv, lane);   // chunk 0

    xvs[t] = xv[b * NN + half * 512 + t];
    xvs[t + 256] = xv[b * NN + half * 512 + t + 256];

    // hoist Q fragments: 4 sets x 8 kc (wave owns 64 q-rows)
    short8 qf[4][8];
    const int qrow0 = b * NN + qt * 256 + wv * 64;
    #pragma unroll
    for (int s = 0; s < 4; s++) {
        const unsigned short* qrow = qb + (size_t)(qrow0 + s * 16 + l15) * PP;
        #pragma unroll
        for (int kc = 0; kc < 8; kc++)
            qf[s][kc] = *reinterpret_cast<const short8*>(qrow + kc * 32 + l4 * 8);
    }

    float den[4][4], num[4][4];
    #pragma unroll
    for (int s = 0; s < 4; s++)
        #pragma unroll
        for (int r = 0; r < 4; r++) { den[s][r] = 0.f; num[s][r] = 0.f; }

    __syncthreads();   // drains stage of chunk 0 + xvs
    int buf = 0;
    for (int mc = 0; mc < 16; mc++) {
        if (mc + 1 < 16) stage32(kbb + (size_t)(mc + 1) * 32 * PP, kt[buf ^ 1], wv, lane);
        #pragma unroll
        for (int st = 0; st < 2; st++) {
            f32x4 z = {0.f, 0.f, 0.f, 0.f};
            f32x4 a[4] = {z, z, z, z};
            #pragma unroll
            for (int kc = 0; kc < 8; kc++) {
                short8 kf = lds_frag(kt[buf], st * 16 + l15, kc * 4 + l4);
                a[0] = __builtin_amdgcn_mfma_f32_16x16x32_bf16(qf[0][kc], kf, a[0], 0, 0, 0);
                a[1] = __builtin_amdgcn_mfma_f32_16x16x32_bf16(qf[1][kc], kf, a[1], 0, 0, 0);
                a[2] = __builtin_amdgcn_mfma_f32_16x16x32_bf16(qf[2][kc], kf, a[2], 0, 0, 0);
                a[3] = __builtin_amdgcn_mfma_f32_16x16x32_bf16(qf[3][kc], kf, a[3], 0, 0, 0);
            }
            float xvv = xvs[mc * 32 + st * 16 + l15];
            #pragma unroll
            for (int s = 0; s < 4; s++)
                #pragma unroll
                for (int r = 0; r < 4; r++) {
                    float e = __expf(a[s][r] * 0.0625f);   // s in (0,16): no max-subtract
                    den[s][r] += e;
                    num[s][r] += e * xvv;
                }
        }
        __syncthreads();
        buf ^= 1;
    }
    // reduce over the 16 lanes (l15 group) holding different m-columns
    #pragma unroll
    for (int s = 0; s < 4; s++)
        #pragma unroll
        for (int r = 0; r < 4; r++) {
            #pragma unroll
            for (int off = 1; off < 16; off <<= 1) {
                den[s][r] += __shfl_xor(den[s][r], off);
                num[s][r] += __shfl_xor(num[s][r], off);
            }
        }
    if (l15 == 0) {
        #pragma unroll
        for (int s = 0; s < 4; s++)
            #pragma unroll
            for (int r = 0; r < 4; r++) {
                int n = qt * 256 + wv * 64 + s * 16 + l4 * 4 + r;
                size_t o = (size_t)half * BB * NN + (size_t)b * NN + n;
                numo[o] = num[s][r];
                deno[o] = den[s][r];
            }
    }
}

// ---- sentence partials: merge num/den halves -> softmax_n -> weighted row sum ----
// Grid (64, 16): 64 rows per chunk.
__global__ __launch_bounds__(256) void sent_partial(const float* __restrict__ x,
                                                    const float* __restrict__ numo,
                                                    const float* __restrict__ deno,
                                                    float* __restrict__ part) {
    __shared__ float al[64];
    __shared__ float redA[4];
    __shared__ float redB[4];
    const int b = blockIdx.x, ch = blockIdx.y;
    const int t = threadIdx.x;
    float l[4];
    #pragma unroll
    for (int i = 0; i < 4; i++) {
        int n = b * NN + t + i * 256;
        l[i] = (numo[n] + numo[BB * NN + n]) / (deno[n] + deno[BB * NN + n]);
    }
    float mx = fmaxf(fmaxf(l[0], l[1]), fmaxf(l[2], l[3]));
    #pragma unroll
    for (int off = 1; off < 64; off <<= 1) mx = fmaxf(mx, __shfl_xor(mx, off));
    if ((t & 63) == 0) redA[t >> 6] = mx;
    __syncthreads();
    mx = fmaxf(fmaxf(redA[0], redA[1]), fmaxf(redA[2], redA[3]));
    float e[4], es = 0.f;
    #pragma unroll
    for (int i = 0; i < 4; i++) { e[i] = __expf(l[i] - mx); es += e[i]; }
    #pragma unroll
    for (int off = 1; off < 64; off <<= 1) es += __shfl_xor(es, off);
    if ((t & 63) == 0) redB[t >> 6] = es;
    __syncthreads();
    float inv = 1.f / (redB[0] + redB[1] + redB[2] + redB[3]);
    // this chunk's 64 rows live at i = ch>>2, threads t in [(ch&3)*64, +64)
    int ei = ch >> 2;
    float sel = (ei == 0) ? e[0] : (ei == 1) ? e[1] : (ei == 2) ? e[2] : e[3];
    if ((t >> 6) == (ch & 3)) al[t & 63] = sel * inv;
    __syncthreads();
    float acc = 0.f;
    const float* xb = x + ((size_t)b * NN + ch * 64) * DD + t;
    #pragma unroll 8
    for (int n = 0; n < 64; n++)
        acc += al[n] * xb[(size_t)n * DD];   // coalesced: thread t reads col t
    part[(b * 16 + ch) * DD + t] = acc;
}

__global__ void sent_final(const float* __restrict__ part, float* __restrict__ out) {
    int b = blockIdx.x, t = threadIdx.x;
    float s = 0.f;
    #pragma unroll
    for (int c = 0; c < 16; c++) s += part[(b * 16 + c) * DD + t];
    out[b * DD + t] = s;
}

extern "C" void kernel_launch(void* const* d_in, const int* in_sizes, int n_in,
                              void* d_out, int out_size, void* d_ws, size_t ws_size,
                              hipStream_t stream) {
    (void)in_sizes; (void)n_in; (void)out_size; (void)ws_size;
    const float* x  = (const float*)d_in[0];
    const float* w1 = (const float*)d_in[1];
    const float* w2 = (const float*)d_in[2];
    const float* w4 = (const float*)d_in[3];
    float* out = (float*)d_out;

    char* ws = (char*)d_ws;
    const size_t MB = 1024 * 1024;
    unsigned short* qb   = (unsigned short*)(ws);                    // 32 MB
    unsigned short* kb   = (unsigned short*)(ws + 32 * MB);          // 32 MB
    unsigned short* wt   = (unsigned short*)(ws + 64 * MB);          // 256 KB
    float*          xv   = (float*)(ws + 64 * MB + 256 * 1024);     // 256 KB
    float*          num  = (float*)(ws + 64 * MB + 512 * 1024);     // 512 KB (2 halves)
    float*          den  = (float*)(ws + 64 * MB + 1024 * 1024);    // 512 KB (2 halves)
    float*          part = (float*)(ws);                             // aliases qb (dead by then)

    prep_wt<<<dim3(2 * PP), dim3(DD), 0, stream>>>(w1, w2, wt);
    qk_fused<<<dim3(BB * NN / 128), dim3(256), 0, stream>>>(x, wt, w4, qb, kb, xv);
    attn_logit<<<dim3(8, BB), dim3(256), 0, stream>>>(qb, kb, xv, num, den);
    sent_partial<<<dim3(BB, 16), dim3(256), 0, stream>>>(x, num, den, part);
    sent_final<<<dim3(BB), dim3(DD), 0, stream>>>(part, out);
}